// Round 2
// baseline (356.908 us; speedup 1.0000x reference)
//
#include <hip/hip_runtime.h>
#include <math.h>

#define N_TOK 4096
#define DIM   512
#define HID   2048
#define NEXP  8
#define NC    7
#define OUT_MIXED (N_TOK*DIM)   // then [lb, ent], then sel_expert[N,2]
#define TM    64                // tokens per MLP tile (M-tile)

typedef __attribute__((ext_vector_type(8))) short bf16x8;
typedef __attribute__((ext_vector_type(4))) float f32x4;

#define HSP 264   // hs row stride (elems): 2-way bank alias only (free)

// ws layout:
//   [64,  +8*4096*4)   int   tok_list[8][4096]   ; expert-0 row reused:
//                        cpad[e*32]  = per-expert count (cpad[0] = arrival ctr)
//                        ipad = floats at +1024B inside the same row
//   [...  +8*4096*4)   float wt_list[8][4096]
//   262208: xbf  [4096][512] bf16                    (4 MB)
//   : W1s  [8][128 ntile][64 kblk][16 n][8 k] bf16   (16 MB)
//   : W2s  [8][32 ntile][256 kblk][16 n][8 k] bf16   (16 MB)
#define OFF_XBF  262208ull
#define OFF_W1S  (OFF_XBF + 4194304ull)
#define OFF_W2S  (OFF_W1S + 16777216ull)
#define WS_REQ   (OFF_W2S + 16777216ull)

__device__ inline unsigned short f2bf(float f) {
  unsigned int u = __builtin_bit_cast(unsigned int, f);
  u = (u + 0x7fffu + ((u >> 16) & 1u)) >> 16;   // RNE
  return (unsigned short)u;
}

// ---------------------------------------------------------------------------
// Fused prep kernel: [0,1024) convert_x | [1024,2048) convert W1 |
// [2048,3072) convert W2 | [3072,3328) router (+out zero, +finalize in last
// arriving router block).
// ---------------------------------------------------------------------------
template<int K, int Nm, int TILES_N>
__device__ void convert_w_body(const float* __restrict__ W,
                               unsigned int* __restrict__ Ws,
                               int blk, int tid,
                               unsigned short lds[32][264])
{
  const int e  = blk >> 7;
  const int rm = blk & 127;
  const int tk = rm / TILES_N;
  const int tn = rm - tk * TILES_N;

  const float* src = W + ((size_t)e * K + tk * 32) * Nm + tn * 256;
#pragma unroll
  for (int it = 0; it < 32; ++it) {
    const int i = it * 256 + tid;
    const int row = i >> 8, col = i & 255;
    lds[row][col] = f2bf(src[(size_t)row * Nm + col]);
  }
  __syncthreads();

  const int ntiles = Nm >> 4, kblks = K >> 3;
#pragma unroll
  for (int it = 0; it < 16; ++it) {
    const int uid   = it * 256 + tid;
    const int nt_l  = uid >> 8;
    const int r     = uid & 255;
    const int kb_l  = r >> 6;
    const int u     = r & 63;
    const int n_lo  = u >> 2;
    const int k_hf  = u & 3;
    const int d_l   = kb_l * 8 + k_hf * 2;
    const int h_l   = nt_l * 16 + n_lo;
    const unsigned int s0 = lds[d_l][h_l], s1 = lds[d_l + 1][h_l];
    const int nt_g = tn * 16 + nt_l;
    const int kb_g = tk * 4 + kb_l;
    const size_t frag = ((size_t)e * ntiles + nt_g) * kblks + kb_g;
    Ws[frag * 64 + n_lo * 4 + k_hf] = s0 | (s1 << 16);
  }
}

__global__ __launch_bounds__(256) void prep_kernel(
    const float* __restrict__ x, const float* __restrict__ rW,
    const float* __restrict__ rb, float* __restrict__ out,
    int* __restrict__ cpad, float* __restrict__ ipad,
    int* __restrict__ tok_list, float* __restrict__ wt_list,
    unsigned short* __restrict__ xbf,
    const float* __restrict__ W1, unsigned int* __restrict__ W1s,
    const float* __restrict__ W2, unsigned int* __restrict__ W2s)
{
  __shared__ unsigned short clds[32][264];
  __shared__ float imp_loc[8];
  __shared__ int   cnt_loc[8];
  __shared__ int   ltok[8][32];
  __shared__ float lwt[8][32];
  __shared__ int   base_s[8];

  const int b   = blockIdx.x;
  const int tid = threadIdx.x;

  if (b < 1024) {                       // ---- convert x -> bf16
    const int g = b * 256 + tid;
    const float* src = x + (size_t)g * 8;
    unsigned short tmp[8];
#pragma unroll
    for (int j = 0; j < 8; ++j) tmp[j] = f2bf(src[j]);
    *(uint4*)(xbf + (size_t)g * 8) = *(const uint4*)tmp;
    return;
  }
  if (b < 2048) { convert_w_body< 512, 2048, 8>(W1, W1s, b - 1024, tid, clds); return; }
  if (b < 3072) { convert_w_body<2048,  512, 2>(W2, W2s, b - 2048, tid, clds); return; }

  // ---- router block (fp32 — sel_expert must be bit-exact)
  const int rb_ = b - 3072;

  { // zero this block's 16 output rows (replaces the 8MB memset dispatch)
    const float4 z = {0.f, 0.f, 0.f, 0.f};
    float4* o4 = (float4*)out + (size_t)rb_ * 2048;
    for (int i = tid; i < 2048; i += 256) o4[i] = z;
  }

  if (tid < 8) { imp_loc[tid] = 0.f; cnt_loc[tid] = 0; }
  __syncthreads();
  const int wave = tid >> 6, lane = tid & 63;

  for (int it = 0; it < 4; ++it) {
    const int t = rb_ * 16 + wave * 4 + it;
    float xv[8];
#pragma unroll
    for (int j = 0; j < 8; ++j) xv[j] = x[(size_t)t*DIM + lane + 64*j];
    float lg[NC];
#pragma unroll
    for (int e = 0; e < NC; ++e) {
      float s = 0.f;
#pragma unroll
      for (int j = 0; j < 8; ++j) s += xv[j] * rW[(lane + 64*j)*NC + e];
      lg[e] = s;
    }
#pragma unroll
    for (int e = 0; e < NC; ++e) {
      float s = lg[e];
#pragma unroll
      for (int off = 32; off > 0; off >>= 1) s += __shfl_xor(s, off, 64);
      lg[e] = s + rb[e];
    }
    int i1 = 0; float l1 = lg[0];
#pragma unroll
    for (int e = 1; e < NC; ++e) { if (lg[e] > l1) { l1 = lg[e]; i1 = e; } }
    int i2 = -1; float l2 = -3.4e38f;
#pragma unroll
    for (int e = 0; e < NC; ++e) { if (e != i1 && lg[e] > l2) { l2 = lg[e]; i2 = e; } }

    const float ed = expf(l2 - l1);
    const float g1 = 1.f/(1.f+ed), g2 = ed/(1.f+ed);

    float p[NC]; float ssum = 0.f;
#pragma unroll
    for (int e = 0; e < NC; ++e) { p[e] = expf(lg[e] - l1); ssum += p[e]; }
    const float inv = 1.f/ssum;

    if (lane == 0) {
#pragma unroll
      for (int e = 0; e < NC; ++e) atomicAdd(&imp_loc[e], p[e]*inv);
      out[OUT_MIXED + 2 + 2*t]     = (float)(i1 + 1);
      out[OUT_MIXED + 2 + 2*t + 1] = (float)(i2 + 1);
      const int e1 = i1 + 1, e2 = i2 + 1;
      int p1 = atomicAdd(&cnt_loc[e1], 1);
      ltok[e1][p1] = t;  lwt[e1][p1] = (2.f/3.f)*g1;
      int p2 = atomicAdd(&cnt_loc[e2], 1);
      ltok[e2][p2] = t;  lwt[e2][p2] = (2.f/3.f)*g2;
    }
  }
  __syncthreads();

  if (tid >= 1 && tid < 8)
    base_s[tid] = atomicAdd(&cpad[tid * 32], cnt_loc[tid]);
  if (tid < NC)
    atomicAdd(&ipad[(tid + 1) * 32], imp_loc[tid]);   // expert e=tid+1 slot
  __syncthreads();

  {
    const int e = tid >> 5, i = tid & 31;
    if (e >= 1 && i < cnt_loc[e]) {
      const int dst = e * N_TOK + base_s[e] + i;
      tok_list[dst] = ltok[e][i];
      wt_list [dst] = lwt[e][i];
    }
  }

  // finalize in the last-arriving router block (replaces finalize_kernel)
  __threadfence();
  __syncthreads();
  if (tid == 0) {
    if (atomicAdd(&cpad[0], 1) == 255) {
      float lb = 0.f, ent = 0.f;
      for (int ee = 0; ee < NC; ++ee) {
        float p = atomicAdd(&ipad[(ee + 1) * 32], 0.f) * (1.f/(float)N_TOK);
        float d = p - (1.f/(float)NC);
        lb += d*d;
        ent -= p * logf(fmaxf(p, 1e-8f));
      }
      out[OUT_MIXED]     = lb * (1.f/(float)NC);
      out[OUT_MIXED + 1] = ent;
    }
  }
}

// ---------------------------------------------------------------------------
// MFMA grouped MLP, TM=64, XCD-locality grid, NO x LDS staging.
// All 8 waves read identical A-fragments -> broadcast via L1: load straight
// from xbf with per-lane token indices held in registers.  LDS = hs only
// (~34 KB) -> 2-3 blocks/CU co-resident (was 1 at 100 KB), single grid wave.
// Grid map (blockIdx%8 == XCD): see round-1 comment; unchanged.
// ---------------------------------------------------------------------------
__global__ __launch_bounds__(512, 4) void moe_mlp_mfma(
    const unsigned short* __restrict__ xbf,
    const unsigned short* __restrict__ W1s,
    const unsigned short* __restrict__ W2s,
    const float* __restrict__ b1, const float* __restrict__ b2,
    const float* __restrict__ fixed_w,
    const int* __restrict__ cpad, const int* __restrict__ tok_list,
    const float* __restrict__ wt_list, float* __restrict__ out)
{
  const int b = blockIdx.x;
  int e, tile, half;
  if (b < 256) {                       // expert 0 (always fully active)
    const int rho = b & 7, u = b >> 3;
    const int quota = (rho < 6) ? 11 : 31;
    if (u >= quota) return;
    const int prefix = (rho < 6) ? rho * 11 : (rho == 6 ? 66 : 97);
    const int unit = prefix + u;       // [0,128)
    e = 0; half = unit >> 6; tile = unit & 63;
  } else {                             // dynamic experts
    const int v = b - 256;
    const int rho = v & 7, u = v >> 3;
    const int cls = ((u >> 6) << 3) + rho;
    if (cls >= 14) return;
    e = (cls >> 1) + 1; half = cls & 1; tile = u & 63;
  }
  const int cnt   = (e == 0) ? N_TOK : cpad[e * 32];
  const int start = tile * TM;
  if (start >= cnt) return;   // uniform per block

  __shared__ __align__(16) unsigned short hs[TM * HSP];  // 33,792 B
  __shared__ int   tok_s[TM];
  __shared__ float wt_s[TM];

  const int tid = threadIdx.x;
  if (tid < TM) {
    int idx = start + tid; int t = 0; float wv = 0.f;
    if (idx < cnt) {
      if (e == 0) { t = idx; wv = (1.f/3.f) * fixed_w[0]; }
      else        { t = tok_list[e*N_TOK + idx]; wv = wt_list[e*N_TOK + idx]; }
    }
    tok_s[tid] = t; wt_s[tid] = wv;
  }
  __syncthreads();

  const int lane = tid & 63;
  const int w    = tid >> 6;          // 0..7
  const int l15  = lane & 15;
  const int q    = lane >> 4;

  // per-lane A-row token indices (rows l15, 16+l15, 32+l15, 48+l15)
  const unsigned short* xrow[4];
#pragma unroll
  for (int mi = 0; mi < 4; ++mi)
    xrow[mi] = xbf + (size_t)tok_s[mi * 16 + l15] * DIM;

  const unsigned short* W1e = W1s + (size_t)e * 128 * 64 * 128;
  const unsigned short* W2e = W2s + (size_t)e * 32 * 256 * 128;

  f32x4 yacc[4][4];
#pragma unroll
  for (int mi = 0; mi < 4; ++mi)
#pragma unroll
    for (int t = 0; t < 4; ++t) yacc[mi][t] = (f32x4){0.f, 0.f, 0.f, 0.f};

  for (int c = half * 4; c < half * 4 + 4; ++c) {
    // ---- phase 1: wave owns 2 n-tiles of this 256-wide hidden chunk, K=512
    f32x4 hacc[4][2];
#pragma unroll
    for (int mi = 0; mi < 4; ++mi)
#pragma unroll
      for (int t = 0; t < 2; ++t) hacc[mi][t] = (f32x4){0.f, 0.f, 0.f, 0.f};
    const int nt_base = c * 16 + w * 2;
#pragma unroll 4
    for (int s = 0; s < 16; ++s) {
      bf16x8 a[4];
#pragma unroll
      for (int mi = 0; mi < 4; ++mi)
        a[mi] = *(const bf16x8*)(xrow[mi] + s * 32 + q * 8);
#pragma unroll
      for (int t = 0; t < 2; ++t) {
        const bf16x8 bb = *(const bf16x8*)(
            W1e + (((size_t)(nt_base + t) * 64) + s * 4 + q) * 128 + l15 * 8);
#pragma unroll
        for (int mi = 0; mi < 4; ++mi)
          hacc[mi][t] = __builtin_amdgcn_mfma_f32_16x16x32_bf16(a[mi], bb, hacc[mi][t], 0, 0, 0);
      }
    }
    // bias + relu -> hs (C layout: row = mi*16 + q*4+reg, col = local n)
#pragma unroll
    for (int t = 0; t < 2; ++t) {
      const float bv = b1[e * HID + (nt_base + t) * 16 + l15];
      const int col = w * 32 + t * 16 + l15;
#pragma unroll
      for (int mi = 0; mi < 4; ++mi)
#pragma unroll
        for (int reg = 0; reg < 4; ++reg)
          hs[(mi*16 + q*4 + reg) * HSP + col] =
              f2bf(fmaxf(hacc[mi][t][reg] + bv, 0.f));
    }
    __syncthreads();

    // ---- phase 2: wave owns 4 output n-tiles (64 of 512 dims), K=256
#pragma unroll 2
    for (int s = 0; s < 8; ++s) {
      bf16x8 a[4];
#pragma unroll
      for (int mi = 0; mi < 4; ++mi)
        a[mi] = *(const bf16x8*)(hs + (mi*16 + l15) * HSP + s * 32 + q * 8);
      const int kblk = c * 32 + s * 4 + q;
#pragma unroll
      for (int t = 0; t < 4; ++t) {
        const bf16x8 bb = *(const bf16x8*)(
            W2e + (((size_t)(w * 4 + t) * 256) + kblk) * 128 + l15 * 8);
#pragma unroll
        for (int mi = 0; mi < 4; ++mi)
          yacc[mi][t] = __builtin_amdgcn_mfma_f32_16x16x32_bf16(a[mi], bb, yacc[mi][t], 0, 0, 0);
      }
    }
    __syncthreads();   // hs consumed before next chunk overwrites
  }

  // ---- epilogue: out[tok] += wt * (y_half + b2*(half==0))
#pragma unroll
  for (int t = 0; t < 4; ++t) {
    const int d = (w * 4 + t) * 16 + l15;
    const float b2v = half ? 0.f : b2[e * DIM + d];
#pragma unroll
    for (int mi = 0; mi < 4; ++mi)
#pragma unroll
      for (int reg = 0; reg < 4; ++reg) {
        const int m = mi*16 + q*4 + reg;
        atomicAdd(&out[(size_t)tok_s[m] * DIM + d], wt_s[m] * (yacc[mi][t][reg] + b2v));
      }
  }
}

// ---------------------------------------------------------------------------
// fp32 fallback path — only if ws_size < WS_REQ
// ---------------------------------------------------------------------------
__global__ __launch_bounds__(256) void router_kernel(
    const float* __restrict__ x, const float* __restrict__ rW,
    const float* __restrict__ rb, float* __restrict__ out,
    int* __restrict__ cpad, float* __restrict__ ipad,
    int* __restrict__ tok_list, float* __restrict__ wt_list)
{
  __shared__ float imp_loc[8];
  __shared__ int   cnt_loc[8];
  __shared__ int   ltok[8][32];
  __shared__ float lwt[8][32];
  __shared__ int   base_s[8];

  const int tid = threadIdx.x;
  if (tid < 8) { imp_loc[tid] = 0.f; cnt_loc[tid] = 0; }
  __syncthreads();
  const int wave = tid >> 6, lane = tid & 63;

  for (int it = 0; it < 4; ++it) {
    const int t = blockIdx.x * 16 + wave * 4 + it;
    float xv[8];
#pragma unroll
    for (int j = 0; j < 8; ++j) xv[j] = x[(size_t)t*DIM + lane + 64*j];
    float lg[NC];
#pragma unroll
    for (int e = 0; e < NC; ++e) {
      float s = 0.f;
#pragma unroll
      for (int j = 0; j < 8; ++j) s += xv[j] * rW[(lane + 64*j)*NC + e];
      lg[e] = s;
    }
#pragma unroll
    for (int e = 0; e < NC; ++e) {
      float s = lg[e];
#pragma unroll
      for (int off = 32; off > 0; off >>= 1) s += __shfl_xor(s, off, 64);
      lg[e] = s + rb[e];
    }
    int i1 = 0; float l1 = lg[0];
#pragma unroll
    for (int e = 1; e < NC; ++e) { if (lg[e] > l1) { l1 = lg[e]; i1 = e; } }
    int i2 = -1; float l2 = -3.4e38f;
#pragma unroll
    for (int e = 0; e < NC; ++e) { if (e != i1 && lg[e] > l2) { l2 = lg[e]; i2 = e; } }

    const float ed = expf(l2 - l1);
    const float g1 = 1.f/(1.f+ed), g2 = ed/(1.f+ed);

    float p[NC]; float ssum = 0.f;
#pragma unroll
    for (int e = 0; e < NC; ++e) { p[e] = expf(lg[e] - l1); ssum += p[e]; }
    const float inv = 1.f/ssum;

    if (lane == 0) {
#pragma unroll
      for (int e = 0; e < NC; ++e) atomicAdd(&imp_loc[e], p[e]*inv);
      out[OUT_MIXED + 2 + 2*t]     = (float)(i1 + 1);
      out[OUT_MIXED + 2 + 2*t + 1] = (float)(i2 + 1);
      const int e1 = i1 + 1, e2 = i2 + 1;
      int p1 = atomicAdd(&cnt_loc[e1], 1);
      ltok[e1][p1] = t;  lwt[e1][p1] = (2.f/3.f)*g1;
      int p2 = atomicAdd(&cnt_loc[e2], 1);
      ltok[e2][p2] = t;  lwt[e2][p2] = (2.f/3.f)*g2;
    }
  }
  __syncthreads();

  if (tid >= 1 && tid < 8)
    base_s[tid] = atomicAdd(&cpad[tid * 32], cnt_loc[tid]);
  if (tid < NC)
    atomicAdd(&ipad[(tid + 1) * 32], imp_loc[tid]);
  __syncthreads();

  {
    const int e = tid >> 5, i = tid & 31;
    if (e >= 1 && i < cnt_loc[e]) {
      const int dst = e * N_TOK + base_s[e] + i;
      tok_list[dst] = ltok[e][i];
      wt_list [dst] = lwt[e][i];
    }
  }
}

__global__ void finalize_kernel(const float* __restrict__ ipad,
                                float* __restrict__ out)
{
  if (threadIdx.x == 0 && blockIdx.x == 0) {
    float lb = 0.f, ent = 0.f;
    for (int e = 0; e < NC; ++e) {
      float p = ipad[(e + 1) * 32] * (1.f/(float)N_TOK);
      float d = p - (1.f/(float)NC);
      lb += d*d;
      ent -= p * logf(fmaxf(p, 1e-8f));
    }
    out[OUT_MIXED]     = lb * (1.f/(float)NC);
    out[OUT_MIXED + 1] = ent;
  }
}

__global__ __launch_bounds__(256) void moe_mlp_kernel(
    const float* __restrict__ x,
    const float* __restrict__ W1, const float* __restrict__ b1,
    const float* __restrict__ W2, const float* __restrict__ b2,
    const float* __restrict__ fixed_w,
    const int* __restrict__ cpad, const int* __restrict__ tok_list,
    const float* __restrict__ wt_list, float* __restrict__ out)
{
  const int e    = blockIdx.x >> 8;
  const int tile = blockIdx.x & 255;
  const int cnt  = (e == 0) ? N_TOK : cpad[e * 32];
  const int start = tile * 16;
  if (start >= cnt) return;

  __shared__ float xs[DIM][17];
  __shared__ float hs2[256][17];
  __shared__ int   tok_s[16];
  __shared__ float wt_s[16];

  const int tid = threadIdx.x;
  if (tid < 16) {
    int idx = start + tid; int t = 0; float w = 0.f;
    if (idx < cnt) {
      if (e == 0) { t = idx; w = (1.f/3.f) * fixed_w[0]; }
      else        { t = tok_list[e*N_TOK + idx]; w = wt_list[e*N_TOK + idx]; }
    }
    tok_s[tid] = t; wt_s[tid] = w;
  }
  __syncthreads();

  for (int i = tid; i < 16*DIM; i += 256) {
    const int m = i >> 9, d = i & (DIM-1);
    xs[d][m] = x[(size_t)tok_s[m]*DIM + d];
  }

  const int r  = tid & 63;
  const int m0 = (tid >> 6) * 4;
  const float* W1e = W1 + (size_t)e * DIM * HID;
  const float* W2e = W2 + (size_t)e * HID * DIM;
  const float* b1e = b1 + e * HID;

  float yacc[4][8];
#pragma unroll
  for (int j = 0; j < 4; ++j)
#pragma unroll
    for (int i = 0; i < 8; ++i) yacc[j][i] = 0.f;

  __syncthreads();

  for (int c = 0; c < 8; ++c) {
    const int k0 = c * 256;
    float bv[4];
#pragma unroll
    for (int i = 0; i < 4; ++i) bv[i] = b1e[k0 + r + 64*i];
    float hacc[4][4];
#pragma unroll
    for (int j = 0; j < 4; ++j)
#pragma unroll
      for (int i = 0; i < 4; ++i) hacc[j][i] = bv[i];
#pragma unroll 2
    for (int d = 0; d < DIM; ++d) {
      float wv[4];
#pragma unroll
      for (int i = 0; i < 4; ++i) wv[i] = W1e[(size_t)d*HID + k0 + r + 64*i];
      float xv[4];
#pragma unroll
      for (int j = 0; j < 4; ++j) xv[j] = xs[d][m0+j];
#pragma unroll
      for (int j = 0; j < 4; ++j)
#pragma unroll
        for (int i = 0; i < 4; ++i) hacc[j][i] += xv[j]*wv[i];
    }
#pragma unroll
    for (int i = 0; i < 4; ++i)
#pragma unroll
      for (int j = 0; j < 4; ++j) hs2[r + 64*i][m0+j] = fmaxf(hacc[j][i], 0.f);
    __syncthreads();

#pragma unroll 2
    for (int k = 0; k < 256; ++k) {
      float wv2[8];
#pragma unroll
      for (int i = 0; i < 8; ++i) wv2[i] = W2e[(size_t)(k0+k)*DIM + r + 64*i];
      float hv[4];
#pragma unroll
      for (int j = 0; j < 4; ++j) hv[j] = hs2[k][m0+j];
#pragma unroll
      for (int j = 0; j < 4; ++j)
#pragma unroll
        for (int i = 0; i < 8; ++i) yacc[j][i] += hv[j]*wv2[i];
    }
    __syncthreads();
  }

#pragma unroll
  for (int i = 0; i < 8; ++i) {
    const int d = r + 64*i;
    const float b2v = b2[e*DIM + d];
#pragma unroll
    for (int j = 0; j < 4; ++j) {
      const int m = m0 + j;
      atomicAdd(&out[(size_t)tok_s[m]*DIM + d], wt_s[m]*(yacc[j][i] + b2v));
    }
  }
}

extern "C" void kernel_launch(void* const* d_in, const int* in_sizes, int n_in,
                              void* d_out, int out_size, void* d_ws, size_t ws_size,
                              hipStream_t stream)
{
  const float* x  = (const float*)d_in[0];
  const float* rW = (const float*)d_in[1];
  const float* rb = (const float*)d_in[2];
  const float* W1 = (const float*)d_in[3];
  const float* b1 = (const float*)d_in[4];
  const float* W2 = (const float*)d_in[5];
  const float* b2 = (const float*)d_in[6];
  const float* fw = (const float*)d_in[7];
  float* out = (float*)d_out;

  int*   tok_list = (int*)((char*)d_ws + 64);
  float* wt_list  = (float*)((char*)d_ws + 64 + (size_t)NEXP*N_TOK*4);
  // counters live inside tok_list's (unused) expert-0 row, contiguous 2KB:
  int*   cpad     = tok_list;                          // [0,1024): counts + arrival ctr
  float* ipad     = (float*)((char*)tok_list + 1024);  // [1024,2048): importance sums

  hipMemsetAsync(cpad, 0, 2048, stream);   // single 2KB clear

  if (ws_size >= WS_REQ) {
    unsigned short* xbf = (unsigned short*)((char*)d_ws + OFF_XBF);
    unsigned int*   W1s = (unsigned int*)((char*)d_ws + OFF_W1S);
    unsigned int*   W2s = (unsigned int*)((char*)d_ws + OFF_W2S);
    prep_kernel<<<3328, 256, 0, stream>>>(x, rW, rb, out, cpad, ipad,
                                          tok_list, wt_list, xbf,
                                          W1, W1s, W2, W2s);
    moe_mlp_mfma<<<1280, 512, 0, stream>>>(xbf, (const unsigned short*)W1s,
                                           (const unsigned short*)W2s, b1, b2, fw,
                                           cpad, tok_list, wt_list, out);
  } else {
    hipMemsetAsync(d_out, 0, (size_t)OUT_MIXED*4, stream);
    router_kernel<<<256, 256, 0, stream>>>(x, rW, rb, out, cpad, ipad,
                                           tok_list, wt_list);
    finalize_kernel<<<1, 64, 0, stream>>>(ipad, out);
    moe_mlp_kernel<<<NEXP*256, 256, 0, stream>>>(x, W1, b1, W2, b2, fw,
                                                 cpad, tok_list, wt_list, out);
  }
}

// Round 3
// 310.803 us; speedup vs baseline: 1.1483x; 1.1483x over previous
//
#include <hip/hip_runtime.h>
#include <math.h>

#define N_TOK 4096
#define DIM   512
#define HID   2048
#define NEXP  8
#define NC    7
#define OUT_MIXED (N_TOK*DIM)   // then [lb, ent], then sel_expert[N,2]
#define TM    64                // tokens per MLP tile (M-tile)

typedef __attribute__((ext_vector_type(8))) short bf16x8;
typedef __attribute__((ext_vector_type(4))) float f32x4;

#define XSP 520   // xs/hs row stride (elems): rows alias banks 2-way only (free)

// ws layout:
//   [64,  +8*4096*4)   int   tok_list[8][4096]   ; expert-0 row reused:
//                        cpad[e*32]  = per-expert count (cpad[0] = arrival ctr)
//                        ipad = floats at +1024B inside the same row
//   [...  +8*4096*4)   float wt_list[8][4096]
//   262208: xbf  [4096][512] bf16                    (4 MB)
//   : W1s  [8][128 ntile][64 kblk][16 n][8 k] bf16   (16 MB)
//   : W2s  [8][32 ntile][256 kblk][16 n][8 k] bf16   (16 MB)
#define OFF_XBF  262208ull
#define OFF_W1S  (OFF_XBF + 4194304ull)
#define OFF_W2S  (OFF_W1S + 16777216ull)
#define WS_REQ   (OFF_W2S + 16777216ull)

__device__ inline unsigned short f2bf(float f) {
  unsigned int u = __builtin_bit_cast(unsigned int, f);
  u = (u + 0x7fffu + ((u >> 16) & 1u)) >> 16;   // RNE
  return (unsigned short)u;
}

// ---------------------------------------------------------------------------
// Fused prep kernel: [0,1024) convert_x | [1024,2048) convert W1 |
// [2048,3072) convert W2 | [3072,3328) router (+out zero, +finalize in last
// arriving router block).
// ---------------------------------------------------------------------------
template<int K, int Nm, int TILES_N>
__device__ void convert_w_body(const float* __restrict__ W,
                               unsigned int* __restrict__ Ws,
                               int blk, int tid,
                               unsigned short lds[32][264])
{
  const int e  = blk >> 7;
  const int rm = blk & 127;
  const int tk = rm / TILES_N;
  const int tn = rm - tk * TILES_N;

  const float* src = W + ((size_t)e * K + tk * 32) * Nm + tn * 256;
#pragma unroll
  for (int it = 0; it < 32; ++it) {
    const int i = it * 256 + tid;
    const int row = i >> 8, col = i & 255;
    lds[row][col] = f2bf(src[(size_t)row * Nm + col]);
  }
  __syncthreads();

  const int ntiles = Nm >> 4, kblks = K >> 3;
#pragma unroll
  for (int it = 0; it < 16; ++it) {
    const int uid   = it * 256 + tid;
    const int nt_l  = uid >> 8;
    const int r     = uid & 255;
    const int kb_l  = r >> 6;
    const int u     = r & 63;
    const int n_lo  = u >> 2;
    const int k_hf  = u & 3;
    const int d_l   = kb_l * 8 + k_hf * 2;
    const int h_l   = nt_l * 16 + n_lo;
    const unsigned int s0 = lds[d_l][h_l], s1 = lds[d_l + 1][h_l];
    const int nt_g = tn * 16 + nt_l;
    const int kb_g = tk * 4 + kb_l;
    const size_t frag = ((size_t)e * ntiles + nt_g) * kblks + kb_g;
    Ws[frag * 64 + n_lo * 4 + k_hf] = s0 | (s1 << 16);
  }
}

__global__ __launch_bounds__(256) void prep_kernel(
    const float* __restrict__ x, const float* __restrict__ rW,
    const float* __restrict__ rb, float* __restrict__ out,
    int* __restrict__ cpad, float* __restrict__ ipad,
    int* __restrict__ tok_list, float* __restrict__ wt_list,
    unsigned short* __restrict__ xbf,
    const float* __restrict__ W1, unsigned int* __restrict__ W1s,
    const float* __restrict__ W2, unsigned int* __restrict__ W2s)
{
  __shared__ unsigned short clds[32][264];
  __shared__ float imp_loc[8];
  __shared__ int   cnt_loc[8];
  __shared__ int   ltok[8][32];
  __shared__ float lwt[8][32];
  __shared__ int   base_s[8];

  const int b   = blockIdx.x;
  const int tid = threadIdx.x;

  if (b < 1024) {                       // ---- convert x -> bf16
    const int g = b * 256 + tid;
    const float* src = x + (size_t)g * 8;
    unsigned short tmp[8];
#pragma unroll
    for (int j = 0; j < 8; ++j) tmp[j] = f2bf(src[j]);
    *(uint4*)(xbf + (size_t)g * 8) = *(const uint4*)tmp;
    return;
  }
  if (b < 2048) { convert_w_body< 512, 2048, 8>(W1, W1s, b - 1024, tid, clds); return; }
  if (b < 3072) { convert_w_body<2048,  512, 2>(W2, W2s, b - 2048, tid, clds); return; }

  // ---- router block (fp32 — sel_expert must be bit-exact)
  const int rb_ = b - 3072;

  { // zero this block's 16 output rows (replaces the 8MB memset dispatch)
    const float4 z = {0.f, 0.f, 0.f, 0.f};
    float4* o4 = (float4*)out + (size_t)rb_ * 2048;
    for (int i = tid; i < 2048; i += 256) o4[i] = z;
  }

  if (tid < 8) { imp_loc[tid] = 0.f; cnt_loc[tid] = 0; }
  __syncthreads();
  const int wave = tid >> 6, lane = tid & 63;

  for (int it = 0; it < 4; ++it) {
    const int t = rb_ * 16 + wave * 4 + it;
    float xv[8];
#pragma unroll
    for (int j = 0; j < 8; ++j) xv[j] = x[(size_t)t*DIM + lane + 64*j];
    float lg[NC];
#pragma unroll
    for (int e = 0; e < NC; ++e) {
      float s = 0.f;
#pragma unroll
      for (int j = 0; j < 8; ++j) s += xv[j] * rW[(lane + 64*j)*NC + e];
      lg[e] = s;
    }
#pragma unroll
    for (int e = 0; e < NC; ++e) {
      float s = lg[e];
#pragma unroll
      for (int off = 32; off > 0; off >>= 1) s += __shfl_xor(s, off, 64);
      lg[e] = s + rb[e];
    }
    int i1 = 0; float l1 = lg[0];
#pragma unroll
    for (int e = 1; e < NC; ++e) { if (lg[e] > l1) { l1 = lg[e]; i1 = e; } }
    int i2 = -1; float l2 = -3.4e38f;
#pragma unroll
    for (int e = 0; e < NC; ++e) { if (e != i1 && lg[e] > l2) { l2 = lg[e]; i2 = e; } }

    const float ed = expf(l2 - l1);
    const float g1 = 1.f/(1.f+ed), g2 = ed/(1.f+ed);

    float p[NC]; float ssum = 0.f;
#pragma unroll
    for (int e = 0; e < NC; ++e) { p[e] = expf(lg[e] - l1); ssum += p[e]; }
    const float inv = 1.f/ssum;

    if (lane == 0) {
#pragma unroll
      for (int e = 0; e < NC; ++e) atomicAdd(&imp_loc[e], p[e]*inv);
      out[OUT_MIXED + 2 + 2*t]     = (float)(i1 + 1);
      out[OUT_MIXED + 2 + 2*t + 1] = (float)(i2 + 1);
      const int e1 = i1 + 1, e2 = i2 + 1;
      int p1 = atomicAdd(&cnt_loc[e1], 1);
      ltok[e1][p1] = t;  lwt[e1][p1] = (2.f/3.f)*g1;
      int p2 = atomicAdd(&cnt_loc[e2], 1);
      ltok[e2][p2] = t;  lwt[e2][p2] = (2.f/3.f)*g2;
    }
  }
  __syncthreads();

  if (tid >= 1 && tid < 8)
    base_s[tid] = atomicAdd(&cpad[tid * 32], cnt_loc[tid]);
  if (tid < NC)
    atomicAdd(&ipad[(tid + 1) * 32], imp_loc[tid]);   // expert e=tid+1 slot
  __syncthreads();

  {
    const int e = tid >> 5, i = tid & 31;
    if (e >= 1 && i < cnt_loc[e]) {
      const int dst = e * N_TOK + base_s[e] + i;
      tok_list[dst] = ltok[e][i];
      wt_list [dst] = lwt[e][i];
    }
  }

  // finalize in the last-arriving router block (replaces finalize_kernel)
  __threadfence();
  __syncthreads();
  if (tid == 0) {
    if (atomicAdd(&cpad[0], 1) == 255) {
      float lb = 0.f, ent = 0.f;
      for (int ee = 0; ee < NC; ++ee) {
        float p = atomicAdd(&ipad[(ee + 1) * 32], 0.f) * (1.f/(float)N_TOK);
        float d = p - (1.f/(float)NC);
        lb += d*d;
        ent -= p * logf(fmaxf(p, 1e-8f));
      }
      out[OUT_MIXED]     = lb * (1.f/(float)NC);
      out[OUT_MIXED + 1] = ent;
    }
  }
}

// ---------------------------------------------------------------------------
// MFMA grouped MLP v3: TM=64, half-split units, XCD-locality grid (as r1).
// Restored LDS x-staging (r2's global A-gather was uncoalesced + L1-thrashed).
// New work split: 8 waves, chunk = 512 hidden (2 chunks per half); each wave
// owns 4 n-tiles in BOTH phases (dup=1: every weight fragment read by exactly
// one wave -> B-traffic 2MB/unit, the per-CU floor) and all 4 M-fragments
// (LDS-A-read : MFMA cycle ratio 0.82, was 1.65).  Barriers: 5/unit (was 9).
// LDS = xs 66.5K + hs 66.5K = 133.6KB -> 1 block/CU; VGPR ~200 (acc 128).
// ---------------------------------------------------------------------------
__global__ __launch_bounds__(512, 2) void moe_mlp_mfma(
    const unsigned short* __restrict__ xbf,
    const unsigned short* __restrict__ W1s,
    const unsigned short* __restrict__ W2s,
    const float* __restrict__ b1, const float* __restrict__ b2,
    const float* __restrict__ fixed_w,
    const int* __restrict__ cpad, const int* __restrict__ tok_list,
    const float* __restrict__ wt_list, float* __restrict__ out)
{
  const int b = blockIdx.x;
  int e, tile, half;
  if (b < 256) {                       // expert 0 (always fully active)
    const int rho = b & 7, u = b >> 3;
    const int quota = (rho < 6) ? 11 : 31;
    if (u >= quota) return;
    const int prefix = (rho < 6) ? rho * 11 : (rho == 6 ? 66 : 97);
    const int unit = prefix + u;       // [0,128)
    e = 0; half = unit >> 6; tile = unit & 63;
  } else {                             // dynamic experts
    const int v = b - 256;
    const int rho = v & 7, u = v >> 3;
    const int cls = ((u >> 6) << 3) + rho;
    if (cls >= 14) return;
    e = (cls >> 1) + 1; half = cls & 1; tile = u & 63;
  }
  const int cnt   = (e == 0) ? N_TOK : cpad[e * 32];
  const int start = tile * TM;
  if (start >= cnt) return;   // uniform per block

  __shared__ __align__(16) unsigned short xs[TM * XSP];  // 66,560 B
  __shared__ __align__(16) unsigned short hs[TM * XSP];  // 66,560 B
  __shared__ int   tok_s[TM];
  __shared__ float wt_s[TM];

  const int tid = threadIdx.x;
  if (tid < TM) {
    int idx = start + tid; int t = 0; float wv = 0.f;
    if (idx < cnt) {
      if (e == 0) { t = idx; wv = (1.f/3.f) * fixed_w[0]; }
      else        { t = tok_list[e*N_TOK + idx]; wv = wt_list[e*N_TOK + idx]; }
    }
    tok_s[tid] = t; wt_s[tid] = wv;
  }
  __syncthreads();

  // stage x tile bf16: 64 rows x 64 16B-chunks (512 threads -> 8 iters)
  for (int i = tid; i < TM * 64; i += 512) {
    const int m = i >> 6, cb = i & 63;
    *(uint4*)(xs + m * XSP + cb * 8) =
        *(const uint4*)(xbf + (size_t)tok_s[m] * DIM + cb * 8);
  }

  const int lane = tid & 63;
  const int wn   = tid >> 6;          // 0..7 : n-tile group owner
  const int l15  = lane & 15;
  const int q    = lane >> 4;

  const unsigned short* W1e = W1s + (size_t)e * 128 * 64 * 128;
  const unsigned short* W2e = W2s + (size_t)e * 32 * 256 * 128;

  f32x4 yacc[4][4];
#pragma unroll
  for (int mi = 0; mi < 4; ++mi)
#pragma unroll
    for (int t = 0; t < 4; ++t) yacc[mi][t] = (f32x4){0.f, 0.f, 0.f, 0.f};

  __syncthreads();   // xs ready

  for (int ch = 0; ch < 2; ++ch) {     // 2 chunks of 512 hidden per half
    // ---- phase 1: wave owns 4 n-tiles of this 512-wide chunk, K=512
    const int ntb = half * 64 + ch * 32 + wn * 4;    // global W1 ntile base
    f32x4 hacc[4][4];
#pragma unroll
    for (int mi = 0; mi < 4; ++mi)
#pragma unroll
      for (int t = 0; t < 4; ++t) hacc[mi][t] = (f32x4){0.f, 0.f, 0.f, 0.f};
#pragma unroll 2
    for (int s = 0; s < 16; ++s) {
      bf16x8 a[4];
#pragma unroll
      for (int mi = 0; mi < 4; ++mi)
        a[mi] = *(const bf16x8*)(xs + (mi*16 + l15) * XSP + s * 32 + q * 8);
#pragma unroll
      for (int t = 0; t < 4; ++t) {
        const bf16x8 bb = *(const bf16x8*)(
            W1e + (((size_t)(ntb + t) * 64) + s * 4 + q) * 128 + l15 * 8);
#pragma unroll
        for (int mi = 0; mi < 4; ++mi)
          hacc[mi][t] = __builtin_amdgcn_mfma_f32_16x16x32_bf16(a[mi], bb, hacc[mi][t], 0, 0, 0);
      }
    }
    // bias + relu -> hs (row = mi*16 + q*4+reg, col in [0,512))
#pragma unroll
    for (int t = 0; t < 4; ++t) {
      const float bv = b1[e * HID + (ntb + t) * 16 + l15];
      const int col = (wn * 4 + t) * 16 + l15;
#pragma unroll
      for (int mi = 0; mi < 4; ++mi)
#pragma unroll
        for (int reg = 0; reg < 4; ++reg)
          hs[(mi*16 + q*4 + reg) * XSP + col] =
              f2bf(fmaxf(hacc[mi][t][reg] + bv, 0.f));
    }
    __syncthreads();

    // ---- phase 2: wave owns 4 output n-tiles (64 of 512 dims), K=512
    const int kb_base = half * 128 + ch * 64;        // global W2 kblk base
#pragma unroll 2
    for (int s = 0; s < 16; ++s) {
      bf16x8 a[4];
#pragma unroll
      for (int mi = 0; mi < 4; ++mi)
        a[mi] = *(const bf16x8*)(hs + (mi*16 + l15) * XSP + s * 32 + q * 8);
      const int kblk = kb_base + s * 4 + q;
#pragma unroll
      for (int t = 0; t < 4; ++t) {
        const bf16x8 bb = *(const bf16x8*)(
            W2e + (((size_t)(wn * 4 + t) * 256) + kblk) * 128 + l15 * 8);
#pragma unroll
        for (int mi = 0; mi < 4; ++mi)
          yacc[mi][t] = __builtin_amdgcn_mfma_f32_16x16x32_bf16(a[mi], bb, yacc[mi][t], 0, 0, 0);
      }
    }
    __syncthreads();   // hs consumed before next chunk overwrites
  }

  // ---- epilogue: out[tok] += wt * (y_half + b2*(half==0))
#pragma unroll
  for (int t = 0; t < 4; ++t) {
    const int d = (wn * 4 + t) * 16 + l15;
    const float b2v = half ? 0.f : b2[e * DIM + d];
#pragma unroll
    for (int mi = 0; mi < 4; ++mi)
#pragma unroll
      for (int reg = 0; reg < 4; ++reg) {
        const int m = mi*16 + q*4 + reg;
        atomicAdd(&out[(size_t)tok_s[m] * DIM + d], wt_s[m] * (yacc[mi][t][reg] + b2v));
      }
  }
}

// ---------------------------------------------------------------------------
// fp32 fallback path — only if ws_size < WS_REQ
// ---------------------------------------------------------------------------
__global__ __launch_bounds__(256) void router_kernel(
    const float* __restrict__ x, const float* __restrict__ rW,
    const float* __restrict__ rb, float* __restrict__ out,
    int* __restrict__ cpad, float* __restrict__ ipad,
    int* __restrict__ tok_list, float* __restrict__ wt_list)
{
  __shared__ float imp_loc[8];
  __shared__ int   cnt_loc[8];
  __shared__ int   ltok[8][32];
  __shared__ float lwt[8][32];
  __shared__ int   base_s[8];

  const int tid = threadIdx.x;
  if (tid < 8) { imp_loc[tid] = 0.f; cnt_loc[tid] = 0; }
  __syncthreads();
  const int wave = tid >> 6, lane = tid & 63;

  for (int it = 0; it < 4; ++it) {
    const int t = blockIdx.x * 16 + wave * 4 + it;
    float xv[8];
#pragma unroll
    for (int j = 0; j < 8; ++j) xv[j] = x[(size_t)t*DIM + lane + 64*j];
    float lg[NC];
#pragma unroll
    for (int e = 0; e < NC; ++e) {
      float s = 0.f;
#pragma unroll
      for (int j = 0; j < 8; ++j) s += xv[j] * rW[(lane + 64*j)*NC + e];
      lg[e] = s;
    }
#pragma unroll
    for (int e = 0; e < NC; ++e) {
      float s = lg[e];
#pragma unroll
      for (int off = 32; off > 0; off >>= 1) s += __shfl_xor(s, off, 64);
      lg[e] = s + rb[e];
    }
    int i1 = 0; float l1 = lg[0];
#pragma unroll
    for (int e = 1; e < NC; ++e) { if (lg[e] > l1) { l1 = lg[e]; i1 = e; } }
    int i2 = -1; float l2 = -3.4e38f;
#pragma unroll
    for (int e = 0; e < NC; ++e) { if (e != i1 && lg[e] > l2) { l2 = lg[e]; i2 = e; } }

    const float ed = expf(l2 - l1);
    const float g1 = 1.f/(1.f+ed), g2 = ed/(1.f+ed);

    float p[NC]; float ssum = 0.f;
#pragma unroll
    for (int e = 0; e < NC; ++e) { p[e] = expf(lg[e] - l1); ssum += p[e]; }
    const float inv = 1.f/ssum;

    if (lane == 0) {
#pragma unroll
      for (int e = 0; e < NC; ++e) atomicAdd(&imp_loc[e], p[e]*inv);
      out[OUT_MIXED + 2 + 2*t]     = (float)(i1 + 1);
      out[OUT_MIXED + 2 + 2*t + 1] = (float)(i2 + 1);
      const int e1 = i1 + 1, e2 = i2 + 1;
      int p1 = atomicAdd(&cnt_loc[e1], 1);
      ltok[e1][p1] = t;  lwt[e1][p1] = (2.f/3.f)*g1;
      int p2 = atomicAdd(&cnt_loc[e2], 1);
      ltok[e2][p2] = t;  lwt[e2][p2] = (2.f/3.f)*g2;
    }
  }
  __syncthreads();

  if (tid >= 1 && tid < 8)
    base_s[tid] = atomicAdd(&cpad[tid * 32], cnt_loc[tid]);
  if (tid < NC)
    atomicAdd(&ipad[(tid + 1) * 32], imp_loc[tid]);
  __syncthreads();

  {
    const int e = tid >> 5, i = tid & 31;
    if (e >= 1 && i < cnt_loc[e]) {
      const int dst = e * N_TOK + base_s[e] + i;
      tok_list[dst] = ltok[e][i];
      wt_list [dst] = lwt[e][i];
    }
  }
}

__global__ void finalize_kernel(const float* __restrict__ ipad,
                                float* __restrict__ out)
{
  if (threadIdx.x == 0 && blockIdx.x == 0) {
    float lb = 0.f, ent = 0.f;
    for (int e = 0; e < NC; ++e) {
      float p = ipad[(e + 1) * 32] * (1.f/(float)N_TOK);
      float d = p - (1.f/(float)NC);
      lb += d*d;
      ent -= p * logf(fmaxf(p, 1e-8f));
    }
    out[OUT_MIXED]     = lb * (1.f/(float)NC);
    out[OUT_MIXED + 1] = ent;
  }
}

__global__ __launch_bounds__(256) void moe_mlp_kernel(
    const float* __restrict__ x,
    const float* __restrict__ W1, const float* __restrict__ b1,
    const float* __restrict__ W2, const float* __restrict__ b2,
    const float* __restrict__ fixed_w,
    const int* __restrict__ cpad, const int* __restrict__ tok_list,
    const float* __restrict__ wt_list, float* __restrict__ out)
{
  const int e    = blockIdx.x >> 8;
  const int tile = blockIdx.x & 255;
  const int cnt  = (e == 0) ? N_TOK : cpad[e * 32];
  const int start = tile * 16;
  if (start >= cnt) return;

  __shared__ float xs[DIM][17];
  __shared__ float hs2[256][17];
  __shared__ int   tok_s[16];
  __shared__ float wt_s[16];

  const int tid = threadIdx.x;
  if (tid < 16) {
    int idx = start + tid; int t = 0; float w = 0.f;
    if (idx < cnt) {
      if (e == 0) { t = idx; w = (1.f/3.f) * fixed_w[0]; }
      else        { t = tok_list[e*N_TOK + idx]; w = wt_list[e*N_TOK + idx]; }
    }
    tok_s[tid] = t; wt_s[tid] = w;
  }
  __syncthreads();

  for (int i = tid; i < 16*DIM; i += 256) {
    const int m = i >> 9, d = i & (DIM-1);
    xs[d][m] = x[(size_t)tok_s[m]*DIM + d];
  }

  const int r  = tid & 63;
  const int m0 = (tid >> 6) * 4;
  const float* W1e = W1 + (size_t)e * DIM * HID;
  const float* W2e = W2 + (size_t)e * HID * DIM;
  const float* b1e = b1 + e * HID;

  float yacc[4][8];
#pragma unroll
  for (int j = 0; j < 4; ++j)
#pragma unroll
    for (int i = 0; i < 8; ++i) yacc[j][i] = 0.f;

  __syncthreads();

  for (int c = 0; c < 8; ++c) {
    const int k0 = c * 256;
    float bv[4];
#pragma unroll
    for (int i = 0; i < 4; ++i) bv[i] = b1e[k0 + r + 64*i];
    float hacc[4][4];
#pragma unroll
    for (int j = 0; j < 4; ++j)
#pragma unroll
      for (int i = 0; i < 4; ++i) hacc[j][i] = bv[i];
#pragma unroll 2
    for (int d = 0; d < DIM; ++d) {
      float wv[4];
#pragma unroll
      for (int i = 0; i < 4; ++i) wv[i] = W1e[(size_t)d*HID + k0 + r + 64*i];
      float xv[4];
#pragma unroll
      for (int j = 0; j < 4; ++j) xv[j] = xs[d][m0+j];
#pragma unroll
      for (int j = 0; j < 4; ++j)
#pragma unroll
        for (int i = 0; i < 4; ++i) hacc[j][i] += xv[j]*wv[i];
    }
#pragma unroll
    for (int i = 0; i < 4; ++i)
#pragma unroll
      for (int j = 0; j < 4; ++j) hs2[r + 64*i][m0+j] = fmaxf(hacc[j][i], 0.f);
    __syncthreads();

#pragma unroll 2
    for (int k = 0; k < 256; ++k) {
      float wv2[8];
#pragma unroll
      for (int i = 0; i < 8; ++i) wv2[i] = W2e[(size_t)(k0+k)*DIM + r + 64*i];
      float hv[4];
#pragma unroll
      for (int j = 0; j < 4; ++j) hv[j] = hs2[k][m0+j];
#pragma unroll
      for (int j = 0; j < 4; ++j)
#pragma unroll
        for (int i = 0; i < 8; ++i) yacc[j][i] += hv[j]*wv2[i];
    }
    __syncthreads();
  }

#pragma unroll
  for (int i = 0; i < 8; ++i) {
    const int d = r + 64*i;
    const float b2v = b2[e*DIM + d];
#pragma unroll
    for (int j = 0; j < 4; ++j) {
      const int m = m0 + j;
      atomicAdd(&out[(size_t)tok_s[m]*DIM + d], wt_s[m]*(yacc[j][i] + b2v));
    }
  }
}

extern "C" void kernel_launch(void* const* d_in, const int* in_sizes, int n_in,
                              void* d_out, int out_size, void* d_ws, size_t ws_size,
                              hipStream_t stream)
{
  const float* x  = (const float*)d_in[0];
  const float* rW = (const float*)d_in[1];
  const float* rb = (const float*)d_in[2];
  const float* W1 = (const float*)d_in[3];
  const float* b1 = (const float*)d_in[4];
  const float* W2 = (const float*)d_in[5];
  const float* b2 = (const float*)d_in[6];
  const float* fw = (const float*)d_in[7];
  float* out = (float*)d_out;

  int*   tok_list = (int*)((char*)d_ws + 64);
  float* wt_list  = (float*)((char*)d_ws + 64 + (size_t)NEXP*N_TOK*4);
  // counters live inside tok_list's (unused) expert-0 row, contiguous 2KB:
  int*   cpad     = tok_list;                          // [0,1024): counts + arrival ctr
  float* ipad     = (float*)((char*)tok_list + 1024);  // [1024,2048): importance sums

  hipMemsetAsync(cpad, 0, 2048, stream);   // single 2KB clear

  if (ws_size >= WS_REQ) {
    unsigned short* xbf = (unsigned short*)((char*)d_ws + OFF_XBF);
    unsigned int*   W1s = (unsigned int*)((char*)d_ws + OFF_W1S);
    unsigned int*   W2s = (unsigned int*)((char*)d_ws + OFF_W2S);
    prep_kernel<<<3328, 256, 0, stream>>>(x, rW, rb, out, cpad, ipad,
                                          tok_list, wt_list, xbf,
                                          W1, W1s, W2, W2s);
    moe_mlp_mfma<<<1280, 512, 0, stream>>>(xbf, (const unsigned short*)W1s,
                                           (const unsigned short*)W2s, b1, b2, fw,
                                           cpad, tok_list, wt_list, out);
  } else {
    hipMemsetAsync(d_out, 0, (size_t)OUT_MIXED*4, stream);
    router_kernel<<<256, 256, 0, stream>>>(x, rW, rb, out, cpad, ipad,
                                           tok_list, wt_list);
    finalize_kernel<<<1, 64, 0, stream>>>(ipad, out);
    moe_mlp_kernel<<<NEXP*256, 256, 0, stream>>>(x, W1, b1, W2, b2, fw,
                                                 cpad, tok_list, wt_list, out);
  }
}